// Round 3
// baseline (367.607 us; speedup 1.0000x reference)
//
#include <hip/hip_runtime.h>
#include <hip/hip_bf16.h>
#include <math.h>

using bf16 = __hip_bfloat16;
typedef short bf16x8 __attribute__((ext_vector_type(8)));
typedef float f32x4 __attribute__((ext_vector_type(4)));

static constexpr int B = 2, S = 2048, D = 1024, H = 16, HD = 64, DFF = 4096;
static constexpr int NR = B * S;   // 4096 rows
static constexpr int DQ = 3072;    // packed QKV row stride
static constexpr float EPS = 1e-5f;

__device__ __forceinline__ bf16 f2b(float v) { return __float2bfloat16(v); }

// async global->LDS, 16B per lane; LDS dest must be wave-uniform base + lane*16
typedef __attribute__((address_space(1))) const void* gp1_t;
typedef __attribute__((address_space(3))) void* sp3_t;
__device__ __forceinline__ void gld_lds16(const bf16* g, bf16* l) {
    __builtin_amdgcn_global_load_lds((gp1_t)(const void*)g, (sp3_t)(void*)l, 16, 0, 0);
}

// ---------------- tiled transpose + fp32->bf16 body: dst[n][k] = src[k][n] ----------
__device__ __forceinline__ void convT_body(const float* __restrict__ src, // [K][N]
                                           bf16* __restrict__ dst,        // [N][K]
                                           int K, int N, int k0, int n0, int tid) {
    __shared__ float tile[64][65];
    const int r = tid >> 4, c = (tid & 15) * 4;
#pragma unroll
    for (int rr = 0; rr < 64; rr += 16) {
        float4 v = *(const float4*)&src[(size_t)(k0 + r + rr) * N + n0 + c];
        tile[r + rr][c] = v.x; tile[r + rr][c + 1] = v.y;
        tile[r + rr][c + 2] = v.z; tile[r + rr][c + 3] = v.w;
    }
    __syncthreads();
    const int n = tid >> 2, ks = (tid & 3) * 16;
    union { bf16 h[16]; int4 v2[2]; } o;
#pragma unroll
    for (int i = 0; i < 16; ++i) o.h[i] = f2b(tile[ks + i][n]);
    bf16* dp = &dst[(size_t)(n0 + n) * K + k0 + ks];
    *(int4*)dp = o.v2[0];
    *(int4*)(dp + 8) = o.v2[1];
}

__global__ __launch_bounds__(256) void convT_kernel(const float* __restrict__ src,
                                                    bf16* __restrict__ dst,
                                                    int K, int N) {
    convT_body(src, dst, K, N, blockIdx.x * 64, blockIdx.y * 64, threadIdx.x);
}

// Batched transpose of the 5 weights known before LN1 (one dispatch, 2048 blocks):
// blocks [0,256) Wq, [256,512) Wk, [512,768) Wv (all into packed WqkvT),
// [768,1024) Wo -> WoT, [1024,2048) W2 -> W2T (K=DFF).
__global__ __launch_bounds__(256) void convT5_kernel(const float* __restrict__ Wq,
                                                     const float* __restrict__ Wk,
                                                     const float* __restrict__ Wv,
                                                     const float* __restrict__ Wo,
                                                     const float* __restrict__ W2,
                                                     bf16* __restrict__ WqkvT,
                                                     bf16* __restrict__ WoT,
                                                     bf16* __restrict__ W2T) {
    const int bid = blockIdx.x;
    const float* src;
    bf16* dst;
    int K, N, bx, by;
    if (bid < 768) {
        const int j = bid >> 8, r = bid & 255;
        src = (j == 0) ? Wq : ((j == 1) ? Wk : Wv);
        dst = WqkvT + (size_t)j * D * D;
        K = D; N = D; bx = r & 15; by = r >> 4;
    } else if (bid < 1024) {
        const int r = bid - 768;
        src = Wo; dst = WoT; K = D; N = D; bx = r & 15; by = r >> 4;
    } else {
        const int r = bid - 1024;
        src = W2; dst = W2T; K = DFF; N = D; bx = r & 63; by = r >> 6;
    }
    convT_body(src, dst, K, N, bx * 64, by * 64, threadIdx.x);
}

// ---------------- LayerNorm: fp32 in, bf16 out; one block per row ----------------
__global__ __launch_bounds__(256) void ln_kernel(const float* __restrict__ x,
                                                 const float* __restrict__ g,
                                                 const float* __restrict__ b,
                                                 bf16* __restrict__ out) {
    const int row = blockIdx.x;
    const int tid = threadIdx.x;
    const float4 v4 = ((const float4*)(x + (size_t)row * D))[tid];
    float v[4] = {v4.x, v4.y, v4.z, v4.w};
    float s = v[0] + v[1] + v[2] + v[3];
    float sq = v[0] * v[0] + v[1] * v[1] + v[2] * v[2] + v[3] * v[3];
#pragma unroll
    for (int off = 32; off >= 1; off >>= 1) {
        s += __shfl_xor(s, off);
        sq += __shfl_xor(sq, off);
    }
    __shared__ float ssum[4], ssq[4];
    const int wave = tid >> 6;
    if ((tid & 63) == 0) { ssum[wave] = s; ssq[wave] = sq; }
    __syncthreads();
    s = ssum[0] + ssum[1] + ssum[2] + ssum[3];
    sq = ssq[0] + ssq[1] + ssq[2] + ssq[3];
    const float mu = s * (1.0f / D);
    const float var = sq * (1.0f / D) - mu * mu;
    const float rstd = rsqrtf(var + EPS);
    bf16* orow = out + (size_t)row * D;
#pragma unroll
    for (int i = 0; i < 4; ++i) {
        const int c = tid * 4 + i;
        orow[c] = f2b((v[i] - mu) * rstd * g[c] + b[c]);
    }
}

// ---------------- GEMM-256: C[M,N] = A @ Bt^T, 256x128 tile, 512 thr, bf16 out ----
// 8 waves in 4x2 (wm=wave>>1 owns rows wm*64.., wn=wave&1 owns cols wn*64..).
// 2 blocks/CU -> 16 waves/CU (50% occ). LDS dbuf, distance-1 prefetch across the
// barrier. Epilogue: stage 128-row halves in LDS, int4 coalesced stores.
// EPI 0: plain. EPI 2: + fp32 bias + exact GELU.
template <int EPI>
__global__ __launch_bounds__(512) void gemm256(const bf16* __restrict__ A,
                                               const bf16* __restrict__ Bt,
                                               const float* __restrict__ bias,
                                               bf16* __restrict__ C,
                                               int M, int N, int K) {
    constexpr int ASZ = 256 * 32, BSZ = 128 * 32;   // elems per buffer
    constexpr int CST = 128 + 8;                    // epilogue stage stride
    __shared__ __align__(16) bf16 smem[2 * (ASZ + BSZ)];  // 48 KB
    // A0 [0,ASZ) A1 [ASZ,2ASZ) B0 [2ASZ,2ASZ+BSZ) B1 [2ASZ+BSZ, ...)

    const int Mtiles = M / 256;
    const int p = blockIdx.x;
    const int tm = p % Mtiles;          // tm-fast: few A strips per XCD
    const int tn = p / Mtiles;
    const int tid = threadIdx.x;
    const int wave = tid >> 6, lane = tid & 63;
    const int wm = wave >> 1, wn = wave & 1;
    const int quad = lane >> 4, l16 = lane & 15;

    f32x4 acc[4][4];
#pragma unroll
    for (int i = 0; i < 4; ++i)
#pragma unroll
        for (int j = 0; j < 4; ++j) acc[i][j] = (f32x4){0.f, 0.f, 0.f, 0.f};

    // A: 1024 slots (2/thread: tid, tid+512); B: 512 slots. slot -> row=s>>2, seg=(s&3)*8
    const int s_row = tid >> 2, s_seg = (tid & 3) * 8;
    const bf16* ApLo = A + (size_t)(tm * 256 + s_row) * K + s_seg;
    const size_t K128 = (size_t)128 * K;
    const bf16* Bp = Bt + (size_t)(tn * 128 + s_row) * K + s_seg;

    // prologue: slab 0 -> buf 0
    gld_lds16(ApLo, smem + tid * 8);
    gld_lds16(ApLo + K128, smem + (512 + tid) * 8);
    gld_lds16(Bp, smem + 2 * ASZ + tid * 8);
    ApLo += 32;
    Bp += 32;

    const int nk = K / 32;
    for (int kt = 0; kt < nk; ++kt) {
        const int cur = kt & 1, nxt = cur ^ 1;
        bf16* Acur = smem + cur * ASZ;
        bf16* Bcur = smem + 2 * ASZ + cur * BSZ;
        __syncthreads();  // drains prefetch issued one full iteration ago
        if (kt + 1 < nk) {
            bf16* Anxt = smem + nxt * ASZ;
            bf16* Bnxt = smem + 2 * ASZ + nxt * BSZ;
            gld_lds16(ApLo, Anxt + tid * 8);
            gld_lds16(ApLo + K128, Anxt + (512 + tid) * 8);
            gld_lds16(Bp, Bnxt + tid * 8);
            ApLo += 32;
            Bp += 32;
        }

        bf16x8 aF[4], bF[4];
#pragma unroll
        for (int mt = 0; mt < 4; ++mt)
            aF[mt] = *(const bf16x8*)(Acur + (wm * 64 + mt * 16 + l16) * 32 + quad * 8);
#pragma unroll
        for (int nt = 0; nt < 4; ++nt)
            bF[nt] = *(const bf16x8*)(Bcur + (wn * 64 + nt * 16 + l16) * 32 + quad * 8);
#pragma unroll
        for (int mt = 0; mt < 4; ++mt)
#pragma unroll
            for (int nt = 0; nt < 4; ++nt)
                acc[mt][nt] = __builtin_amdgcn_mfma_f32_16x16x32_bf16(
                    aF[mt], bF[nt], acc[mt][nt], 0, 0, 0);
    }

    // epilogue in two 128-row halves. C/D layout: col = lane&15, row = quad*4+j.
#pragma unroll
    for (int hh = 0; hh < 2; ++hh) {
        __syncthreads();  // prev reads (k-loop or prev half's write-out) done
        if ((wm >> 1) == hh) {
#pragma unroll
            for (int nt = 0; nt < 4; ++nt) {
                const int ccol = wn * 64 + nt * 16 + l16;
                float bv = 0.f;
                if (EPI == 2) bv = bias[tn * 128 + ccol];
#pragma unroll
                for (int mt = 0; mt < 4; ++mt) {
                    const int r0 = (wm & 1) * 64 + mt * 16 + quad * 4;
#pragma unroll
                    for (int j = 0; j < 4; ++j) {
                        float v = acc[mt][nt][j];
                        if (EPI == 2) {
                            v += bv;
                            v = 0.5f * v * (1.0f + erff(v * 0.70710678118654752f));
                        }
                        smem[(r0 + j) * CST + ccol] = f2b(v);
                    }
                }
            }
        }
        __syncthreads();
        // write-out: 128x128 half-tile = 2048 int4; 4 per thread
        bf16* crow = C + (size_t)(tm * 256 + hh * 128) * N + tn * 128;
#pragma unroll
        for (int i = 0; i < 4; ++i) {
            const int gid = i * 512 + tid;
            const int row = gid >> 4, c8 = gid & 15;
            const int4 val = *(const int4*)(smem + row * CST + c8 * 8);
            *(int4*)(crow + (size_t)row * N + c8 * 8) = val;
        }
    }
}

// ---------------- GEMM: C[M,N] = A[M,K] @ Bt[N,K]^T  (128xBN, 256 thr) ----------
// K is the per-block K length (split-K slice); Kld is the row stride of A/Bt.
// Grid may carry a split-K dim: ks = blockIdx.x / (Mtiles * N/BN).
// EPI 1: + fp32 bias + fp32 residual, fp32 out (res==C in-place OK).
// EPI 3: raw fp32 partial store to ((float*)Cv) + ks*M*N (no bias/res).
template <int EPI, int BN, int TPB>
__global__ __launch_bounds__(256) void gemm_bt(const bf16* __restrict__ A,
                                               const bf16* __restrict__ Bt,
                                               const float* __restrict__ bias,
                                               const float* __restrict__ res,
                                               void* __restrict__ Cv,
                                               int M, int N, int K, int Kld) {
    constexpr int NTW = BN / 32;
    constexpr int ASZ = 128 * 32, BSZ = BN * 32;
    __shared__ __align__(16) bf16 smem[2 * (ASZ + BSZ)];

    const int Mtiles = M / 128;
    const int T = Mtiles * (N / BN) / TPB;   // tiles per K-split
    const int p0 = blockIdx.x;
    const int ks = p0 / T;
    const int p = p0 % T;
    const int tm = p % Mtiles;
    const int tn0 = (p / Mtiles) * TPB;
    const int tid = threadIdx.x;
    const int wave = tid >> 6, lane = tid & 63;
    const int wm = wave >> 1, wn = wave & 1;
    const int quad = lane >> 4, l16 = lane & 15;

    A += (size_t)ks * K;    // advance along K for this split
    Bt += (size_t)ks * K;

    const int s_row = tid >> 2, s_seg = (tid & 3) * 8;
    const size_t K64 = (size_t)64 * Kld;
    const int nk = K / 32;

    for (int tp = 0; tp < TPB; ++tp) {
        const int tn = tn0 + tp;
        if (tp) __syncthreads();

        f32x4 acc[4][NTW];
#pragma unroll
        for (int i = 0; i < 4; ++i)
#pragma unroll
            for (int j = 0; j < NTW; ++j) acc[i][j] = (f32x4){0.f, 0.f, 0.f, 0.f};

        const bf16* Ap = A + (size_t)(tm * 128 + s_row) * Kld + s_seg;
        const bf16* Bp = Bt + (size_t)(tn * BN + s_row) * Kld + s_seg;

        gld_lds16(Ap, smem + tid * 8);
        gld_lds16(Ap + K64, smem + (256 + tid) * 8);
        gld_lds16(Bp, smem + 2 * ASZ + tid * 8);
        if constexpr (BN == 128) gld_lds16(Bp + K64, smem + 2 * ASZ + (256 + tid) * 8);
        Ap += 32;
        Bp += 32;

        for (int kt = 0; kt < nk; ++kt) {
            const int cur = kt & 1, nxt = cur ^ 1;
            bf16* Acur = smem + cur * ASZ;
            bf16* Bcur = smem + 2 * ASZ + cur * BSZ;
            __syncthreads();
            if (kt + 1 < nk) {
                bf16* Anxt = smem + nxt * ASZ;
                bf16* Bnxt = smem + 2 * ASZ + nxt * BSZ;
                gld_lds16(Ap, Anxt + tid * 8);
                gld_lds16(Ap + K64, Anxt + (256 + tid) * 8);
                gld_lds16(Bp, Bnxt + tid * 8);
                if constexpr (BN == 128) gld_lds16(Bp + K64, Bnxt + (256 + tid) * 8);
                Ap += 32;
                Bp += 32;
            }

            bf16x8 aF[4], bF[NTW];
#pragma unroll
            for (int mt = 0; mt < 4; ++mt)
                aF[mt] = *(const bf16x8*)(Acur + (wm * 64 + mt * 16 + l16) * 32 + quad * 8);
#pragma unroll
            for (int nt = 0; nt < NTW; ++nt)
                bF[nt] = *(const bf16x8*)(Bcur + (wn * (BN / 2) + nt * 16 + l16) * 32 + quad * 8);
#pragma unroll
            for (int mt = 0; mt < 4; ++mt)
#pragma unroll
                for (int nt = 0; nt < NTW; ++nt)
                    acc[mt][nt] = __builtin_amdgcn_mfma_f32_16x16x32_bf16(
                        aF[mt], bF[nt], acc[mt][nt], 0, 0, 0);
        }

        if constexpr (EPI == 1) {
            // fp32 + bias + residual, direct stores
#pragma unroll
            for (int nt = 0; nt < NTW; ++nt) {
                const int col = tn * BN + wn * (BN / 2) + nt * 16 + l16;
                const float bv = bias[col];
#pragma unroll
                for (int mt = 0; mt < 4; ++mt) {
                    const int row0 = tm * 128 + wm * 64 + mt * 16 + quad * 4;
#pragma unroll
                    for (int j = 0; j < 4; ++j) {
                        const size_t idx = (size_t)(row0 + j) * N + col;
                        ((float*)Cv)[idx] = acc[mt][nt][j] + bv + res[idx];
                    }
                }
            }
        } else {
            // EPI 3: raw fp32 partial into slice ks
            float* P = (float*)Cv + (size_t)ks * M * N;
#pragma unroll
            for (int nt = 0; nt < NTW; ++nt) {
                const int col = tn * BN + wn * (BN / 2) + nt * 16 + l16;
#pragma unroll
                for (int mt = 0; mt < 4; ++mt) {
                    const int row0 = tm * 128 + wm * 64 + mt * 16 + quad * 4;
#pragma unroll
                    for (int j = 0; j < 4; ++j)
                        P[(size_t)(row0 + j) * N + col] = acc[mt][nt][j];
                }
            }
        }
    }
}

// ---------------- split-K reduce: out = p0 + p1 + bias + res (res may alias out) ----
__global__ __launch_bounds__(256) void reduce2_kernel(float* __restrict__ out,
                                                      const float* __restrict__ p0,
                                                      const float* __restrict__ p1,
                                                      const float* __restrict__ bias,
                                                      const float* __restrict__ res) {
    const size_t i4 = ((size_t)blockIdx.x * 256 + threadIdx.x) * 4;
    const float4 a = *(const float4*)(p0 + i4);
    const float4 b = *(const float4*)(p1 + i4);
    const float4 r = *(const float4*)(res + i4);
    const float4 bv = *(const float4*)(bias + ((int)i4 & (D - 1)));
    float4 o;
    o.x = a.x + b.x + r.x + bv.x;
    o.y = a.y + b.y + r.y + bv.y;
    o.z = a.z + b.z + r.z + bv.z;
    o.w = a.w + b.w + r.w + bv.w;
    *(float4*)(out + i4) = o;
}

// ---------------- MFMA flash attention (causal), 2 blocks/CU ----------
// Grid 512 (1-D): bh = id&31 (id%8 = bh%8 -> per-head XCD locality), k = id>>5,
// t = k<8 ? 15-k : k-8 (snake: co-resident pairs sum to 34 chunks; big tiles
// dispatched first). 512 threads = 8 waves x 16 q-rows = one 128-query tile.
// K/V double-buffered, distance-1 prefetch, one barrier per 64-key chunk.
//
// SWAPPED-OPERAND layout: QK^T computed as mfma(K,Q) -> sc[key][q=l16]; each
// lane owns one q-row, so online-softmax max/sum are in-register + 2 shuffles.
// PV computed as mfma(V,P) -> O[d][q=l16]; alpha-rescale and 1/l are lane-local
// scalars (no broadcast shuffles). 1/sqrt(HD)=0.125 pre-folded into Q (exact
// in bf16: power of two).
__global__ __launch_bounds__(512) void fattn_kernel(const bf16* __restrict__ QKV,
                                                    bf16* __restrict__ ctx) {
    const int id = blockIdx.x;
    const int bh = id & 31;
    const int k = id >> 5;          // 0..15
    const int t = (k < 8) ? 15 - k : k - 8;
    const int b = bh >> 4, h = bh & (H - 1);
    const int tid = threadIdx.x;
    const int wave = tid >> 6, lane = tid & 63;
    const int quad = lane >> 4, l16 = lane & 15;
    const bf16* Qp = QKV + (size_t)b * S * DQ + h * HD;
    const bf16* Kp = Qp + D;
    const bf16* Vp = Qp + 2 * D;

    __shared__ __align__(16) bf16 Ks[2][64 * 64];  // swizzled [key][dseg]
    __shared__ __align__(16) bf16 Vt[2][64][72];   // [d][key]
    __shared__ __align__(16) bf16 Ps[128][76];     // [q][key], wave-private rows

    // K staging: 1 slot (16B) per thread; slot = key*8 + (dseg ^ (key&7))
    const int keyA = tid >> 3, dsA = ((tid & 7) ^ (keyA & 7)) * 8;

    const int q0 = t * 128;
    // Q fragments, pre-scaled by 1/sqrt(64); wave w owns q-rows [w*16, w*16+16)
    const bf16* qg = Qp + (size_t)(q0 + wave * 16 + l16) * DQ + quad * 8;
    union U8 { bf16 h[8]; bf16x8 v; };
    U8 uq0, uq1;
    uq0.v = *(const bf16x8*)(qg);
    uq1.v = *(const bf16x8*)(qg + 32);
#pragma unroll
    for (int i = 0; i < 8; ++i) {
        uq0.h[i] = f2b(__bfloat162float(uq0.h[i]) * 0.125f);
        uq1.h[i] = f2b(__bfloat162float(uq1.h[i]) * 0.125f);
    }
    const bf16x8 aQ0 = uq0.v;
    const bf16x8 aQ1 = uq1.v;

    f32x4 O[4];   // transposed: O[nt][j] = O[d = nt*16+quad*4+j][q = l16]
#pragma unroll
    for (int nt = 0; nt < 4; ++nt) O[nt] = (f32x4){0.f, 0.f, 0.f, 0.f};
    float rowm = -3.0e38f, rowl = 0.f;   // per-lane: q = l16

    // pre-stage chunk 0 into buffer 0
    gld_lds16(Kp + (size_t)keyA * DQ + dsA, Ks[0] + tid * 8);
    {
        // V: wave w stages d in [w*8, w*8+8), key = lane
        const bf16* vg = Vp + (size_t)lane * DQ + wave * 8;
        union { int4 v; bf16 hh[8]; } u;
        u.v = *(const int4*)vg;
#pragma unroll
        for (int i = 0; i < 8; ++i) Vt[0][wave * 8 + i][lane] = u.hh[i];
    }

    const int nch = 2 * t + 2;
    for (int c = 0; c < nch; ++c) {
        const int cur = c & 1, nxt = cur ^ 1;
        __syncthreads();  // buf[cur] ready (drains prefetch vmcnt + V lgkm)
        // prefetch chunk c+1 into buf[nxt]
        union { int4 v; bf16 hh[8]; } u;
        if (c < nch - 1) {
            const int k1 = (c + 1) * 64;
            gld_lds16(Kp + (size_t)(k1 + keyA) * DQ + dsA, Ks[nxt] + tid * 8);
            u.v = *(const int4*)(Vp + (size_t)(k1 + lane) * DQ + wave * 8);
        }

        // swapped scores: sc[nt][j] = S[key = nt*16+quad*4+j][q = l16]
        f32x4 sc[4];
#pragma unroll
        for (int nt = 0; nt < 4; ++nt) {
            const int r = nt * 16 + l16;
            const bf16x8 bK0 = *(const bf16x8*)(Ks[cur] + (r * 8 + (quad ^ (r & 7))) * 8);
            const bf16x8 bK1 = *(const bf16x8*)(Ks[cur] + (r * 8 + ((4 + quad) ^ (r & 7))) * 8);
            f32x4 z = (f32x4){0.f, 0.f, 0.f, 0.f};
            z = __builtin_amdgcn_mfma_f32_16x16x32_bf16(bK0, aQ0, z, 0, 0, 0);
            z = __builtin_amdgcn_mfma_f32_16x16x32_bf16(bK1, aQ1, z, 0, 0, 0);
            sc[nt] = z;
        }
        // causal mask — last two chunks intersect the 128-row diagonal band
        if (c >= 2 * t) {
            const int kb0 = (c - 2 * t) * 64 + quad * 4;
            const int qr = wave * 16 + l16;
#pragma unroll
            for (int nt = 0; nt < 4; ++nt)
#pragma unroll
                for (int j = 0; j < 4; ++j)
                    if (kb0 + nt * 16 + j > qr) sc[nt][j] = -3.0e38f;
        }
        // online softmax, lane-local row (q = l16); reduce over quads only
        f32x4 mv;
#pragma unroll
        for (int j = 0; j < 4; ++j)
            mv[j] = fmaxf(fmaxf(sc[0][j], sc[1][j]), fmaxf(sc[2][j], sc[3][j]));
        float mx = fmaxf(fmaxf(mv[0], mv[1]), fmaxf(mv[2], mv[3]));
        mx = fmaxf(mx, __shfl_xor(mx, 16));
        mx = fmaxf(mx, __shfl_xor(mx, 32));
        const float mn = fmaxf(rowm, mx);
        const float alq = __expf(rowm - mn);
        rowm = mn;
        float rs = 0.f;
#pragma unroll
        for (int nt = 0; nt < 4; ++nt)
#pragma unroll
            for (int j = 0; j < 4; ++j) {
                sc[nt][j] = __expf(sc[nt][j] - mn);
                rs += sc[nt][j];
            }
        rs += __shfl_xor(rs, 16);
        rs += __shfl_xor(rs, 32);
        rowl = rowl * alq + rs;

        // P transpose via LDS: lane writes 4 consecutive keys of row q=l16 (b64)
        const int prow = wave * 16 + l16;
#pragma unroll
        for (int nt = 0; nt < 4; ++nt) {
            union { bf16 h[4]; int2 v; } pk;
#pragma unroll
            for (int j = 0; j < 4; ++j) pk.h[j] = f2b(sc[nt][j]);
            *(int2*)&Ps[prow][nt * 16 + quad * 4] = pk.v;
        }
        asm volatile("s_waitcnt lgkmcnt(0)" ::: "memory");
        const bf16x8 aP0 = *(const bf16x8*)&Ps[prow][quad * 8];
        const bf16x8 aP1 = *(const bf16x8*)&Ps[prow][32 + quad * 8];
        // O = O*alpha + V^T P   (alpha lane-local since O cols = q = l16)
#pragma unroll
        for (int nt = 0; nt < 4; ++nt)
#pragma unroll
            for (int j = 0; j < 4; ++j) O[nt][j] *= alq;
#pragma unroll
        for (int nt = 0; nt < 4; ++nt) {
            const bf16x8 bV0 = *(const bf16x8*)&Vt[cur][nt * 16 + l16][quad * 8];
            const bf16x8 bV1 = *(const bf16x8*)&Vt[cur][nt * 16 + l16][32 + quad * 8];
            O[nt] = __builtin_amdgcn_mfma_f32_16x16x32_bf16(bV0, aP0, O[nt], 0, 0, 0);
            O[nt] = __builtin_amdgcn_mfma_f32_16x16x32_bf16(bV1, aP1, O[nt], 0, 0, 0);
        }
        // commit prefetched V into buf[nxt]
        if (c < nch - 1) {
#pragma unroll
            for (int i = 0; i < 8; ++i) Vt[nxt][wave * 8 + i][lane] = u.hh[i];
        }
    }

    // finalize: lane holds q = l16, d = nt*16+quad*4+j; 8B stores per nt
    const float rlq = 1.0f / rowl;
    bf16* crow = ctx + (size_t)b * S * D + h * HD + (size_t)(q0 + wave * 16 + l16) * D;
#pragma unroll
    for (int nt = 0; nt < 4; ++nt) {
        union { bf16 h[4]; int2 v; } o;
#pragma unroll
        for (int j = 0; j < 4; ++j) o.h[j] = f2b(O[nt][j] * rlq);
        *(int2*)(crow + nt * 16 + quad * 4) = o.v;
    }
}

// ---------------- launcher ----------------
extern "C" void kernel_launch(void* const* d_in, const int* in_sizes, int n_in,
                              void* d_out, int out_size, void* d_ws, size_t ws_size,
                              hipStream_t stream) {
    const float* x     = (const float*)d_in[0];
    const float* ln1_g = (const float*)d_in[1];
    const float* ln1_b = (const float*)d_in[2];
    const float* Wq    = (const float*)d_in[3];
    const float* Wk    = (const float*)d_in[4];
    const float* Wv    = (const float*)d_in[5];
    const float* Wo    = (const float*)d_in[6];
    const float* bo    = (const float*)d_in[7];
    const float* ln2_g = (const float*)d_in[8];
    const float* ln2_b = (const float*)d_in[9];
    const float* W1    = (const float*)d_in[10];
    const float* b1    = (const float*)d_in[11];
    const float* W2    = (const float*)d_in[12];
    const float* b2    = (const float*)d_in[13];
    float* out = (float*)d_out;

    // workspace (MB), lifetime-overlapped; base peak 64 MB:
    //   [ 0, 8): h (LN1 out)            -> W1T (conv after QKV gemm)
    //   [ 8,32): QKVb (packed, 24 MB)   \
    //   [32,40): ctx (attn out)          } -> hff [8,40) (32 MB)
    //   [40,48): h2 (LN2 out)
    //   [48,54): WqkvT   [54,56): WoT   [56,64): W2T
    //   [64,96): split-K fp32 partials for W2 (only if ws_size >= 96 MB)
    //   x2 (fp32 residual) lives in d_out; final GEMM reads it in-place.
    char* ws = (char*)d_ws;
    const size_t MB = (size_t)1 << 20;
    bf16* h     = (bf16*)(ws + 0 * MB);
    bf16* W1T   = (bf16*)(ws + 0 * MB);
    bf16* QKVb  = (bf16*)(ws + 8 * MB);
    bf16* hff   = (bf16*)(ws + 8 * MB);
    bf16* ctx   = (bf16*)(ws + 32 * MB);
    bf16* h2    = (bf16*)(ws + 40 * MB);
    bf16* WqkvT = (bf16*)(ws + 48 * MB);
    bf16* WoT   = (bf16*)(ws + 54 * MB);
    bf16* W2T   = (bf16*)(ws + 56 * MB);
    float* pK   = (float*)(ws + 64 * MB);   // 2 x 16 MB partials

    // --- 0) transpose-convert the 5 x-independent weights in ONE dispatch ---
    convT5_kernel<<<2048, 256, 0, stream>>>(Wq, Wk, Wv, Wo, W2, WqkvT, WoT, W2T);
    // --- 1) LN1 ---
    ln_kernel<<<NR, 256, 0, stream>>>(x, ln1_g, ln1_b, h);
    // --- 2) QKV = h @ [Wq|Wk|Wv]   [4096,1024]x[1024,3072], 384 big blocks ---
    gemm256<0><<<(NR / 256) * (DQ / 128), 512, 0, stream>>>(
        h, WqkvT, nullptr, QKVb, NR, DQ, D);
    // h dead now -> W1T into [0,8)
    convT_kernel<<<dim3(16, 64), 256, 0, stream>>>(W1, W1T, D, DFF);
    // --- 3) flash attention -> ctx (512 blocks, 2/CU) ---
    fattn_kernel<<<dim3((S / 128) * B * H), 512, 0, stream>>>(QKVb, ctx);
    // --- 4) x2 = x + ctx @ Wo + bo   (fp32 into d_out), 512 blocks ---
    gemm_bt<1, 64, 1><<<(NR / 128) * (D / 64), 256, 0, stream>>>(
        ctx, WoT, bo, x, out, NR, D, D, D);
    // --- 5) LN2 ---
    ln_kernel<<<NR, 256, 0, stream>>>(out, ln2_g, ln2_b, h2);
    // --- 6) hff = gelu(h2 @ W1 + b1), 512 big blocks (2/CU, one generation) ---
    gemm256<2><<<(NR / 256) * (DFF / 128), 512, 0, stream>>>(
        h2, W1T, b1, hff, NR, DFF, D);
    // --- 7) out = x2 + hff @ W2 + b2   [4096,4096]x[4096,1024], in-place ---
    if (ws_size >= 96 * MB) {
        // split-K=2, BN=64: grid 32*16*2 = 1024 blocks -> 4 blocks/CU, 16 waves/CU
        // (round-2 BN=128/512-block config had only 8 waves/CU -> no overlap gain).
        gemm_bt<3, 64, 1><<<(NR / 128) * (D / 64) * 2, 256, 0, stream>>>(
            hff, W2T, nullptr, nullptr, pK, NR, D, DFF / 2, DFF);
        reduce2_kernel<<<NR * D / 1024, 256, 0, stream>>>(
            out, pK, pK + (size_t)NR * D, b2, out);
    } else {
        gemm_bt<1, 64, 1><<<(NR / 128) * (D / 64), 256, 0, stream>>>(
            hff, W2T, b2, out, out, NR, D, DFF, DFF);
    }
}

// Round 4
// 355.500 us; speedup vs baseline: 1.0341x; 1.0341x over previous
//
#include <hip/hip_runtime.h>
#include <hip/hip_bf16.h>
#include <math.h>

using bf16 = __hip_bfloat16;
typedef short bf16x8 __attribute__((ext_vector_type(8)));
typedef float f32x4 __attribute__((ext_vector_type(4)));

static constexpr int B = 2, S = 2048, D = 1024, H = 16, HD = 64, DFF = 4096;
static constexpr int NR = B * S;   // 4096 rows
static constexpr int DQ = 3072;    // packed QKV row stride
static constexpr float EPS = 1e-5f;

__device__ __forceinline__ bf16 f2b(float v) { return __float2bfloat16(v); }

// async global->LDS, 16B per lane; LDS dest must be wave-uniform base + lane*16
typedef __attribute__((address_space(1))) const void* gp1_t;
typedef __attribute__((address_space(3))) void* sp3_t;
__device__ __forceinline__ void gld_lds16(const bf16* g, bf16* l) {
    __builtin_amdgcn_global_load_lds((gp1_t)(const void*)g, (sp3_t)(void*)l, 16, 0, 0);
}

// ---------------- tiled transpose + fp32->bf16 body: dst[n][k] = src[k][n] ----------
__device__ __forceinline__ void convT_body(const float* __restrict__ src, // [K][N]
                                           bf16* __restrict__ dst,        // [N][K]
                                           int K, int N, int k0, int n0, int tid) {
    __shared__ float tile[64][65];
    const int r = tid >> 4, c = (tid & 15) * 4;
#pragma unroll
    for (int rr = 0; rr < 64; rr += 16) {
        float4 v = *(const float4*)&src[(size_t)(k0 + r + rr) * N + n0 + c];
        tile[r + rr][c] = v.x; tile[r + rr][c + 1] = v.y;
        tile[r + rr][c + 2] = v.z; tile[r + rr][c + 3] = v.w;
    }
    __syncthreads();
    const int n = tid >> 2, ks = (tid & 3) * 16;
    union { bf16 h[16]; int4 v2[2]; } o;
#pragma unroll
    for (int i = 0; i < 16; ++i) o.h[i] = f2b(tile[ks + i][n]);
    bf16* dp = &dst[(size_t)(n0 + n) * K + k0 + ks];
    *(int4*)dp = o.v2[0];
    *(int4*)(dp + 8) = o.v2[1];
}

__global__ __launch_bounds__(256) void convT_kernel(const float* __restrict__ src,
                                                    bf16* __restrict__ dst,
                                                    int K, int N) {
    convT_body(src, dst, K, N, blockIdx.x * 64, blockIdx.y * 64, threadIdx.x);
}

// Batched transpose of the 5 weights known before LN1 (one dispatch, 2048 blocks)
__global__ __launch_bounds__(256) void convT5_kernel(const float* __restrict__ Wq,
                                                     const float* __restrict__ Wk,
                                                     const float* __restrict__ Wv,
                                                     const float* __restrict__ Wo,
                                                     const float* __restrict__ W2,
                                                     bf16* __restrict__ WqkvT,
                                                     bf16* __restrict__ WoT,
                                                     bf16* __restrict__ W2T) {
    const int bid = blockIdx.x;
    const float* src;
    bf16* dst;
    int K, N, bx, by;
    if (bid < 768) {
        const int j = bid >> 8, r = bid & 255;
        src = (j == 0) ? Wq : ((j == 1) ? Wk : Wv);
        dst = WqkvT + (size_t)j * D * D;
        K = D; N = D; bx = r & 15; by = r >> 4;
    } else if (bid < 1024) {
        const int r = bid - 768;
        src = Wo; dst = WoT; K = D; N = D; bx = r & 15; by = r >> 4;
    } else {
        const int r = bid - 1024;
        src = W2; dst = W2T; K = DFF; N = D; bx = r & 63; by = r >> 6;
    }
    convT_body(src, dst, K, N, bx * 64, by * 64, threadIdx.x);
}

// ---------------- LayerNorm: fp32 in, bf16 out; one block per row ----------------
__global__ __launch_bounds__(256) void ln_kernel(const float* __restrict__ x,
                                                 const float* __restrict__ g,
                                                 const float* __restrict__ b,
                                                 bf16* __restrict__ out) {
    const int row = blockIdx.x;
    const int tid = threadIdx.x;
    const float4 v4 = ((const float4*)(x + (size_t)row * D))[tid];
    float v[4] = {v4.x, v4.y, v4.z, v4.w};
    float s = v[0] + v[1] + v[2] + v[3];
    float sq = v[0] * v[0] + v[1] * v[1] + v[2] * v[2] + v[3] * v[3];
#pragma unroll
    for (int off = 32; off >= 1; off >>= 1) {
        s += __shfl_xor(s, off);
        sq += __shfl_xor(sq, off);
    }
    __shared__ float ssum[4], ssq[4];
    const int wave = tid >> 6;
    if ((tid & 63) == 0) { ssum[wave] = s; ssq[wave] = sq; }
    __syncthreads();
    s = ssum[0] + ssum[1] + ssum[2] + ssum[3];
    sq = ssq[0] + ssq[1] + ssq[2] + ssq[3];
    const float mu = s * (1.0f / D);
    const float var = sq * (1.0f / D) - mu * mu;
    const float rstd = rsqrtf(var + EPS);
    bf16* orow = out + (size_t)row * D;
#pragma unroll
    for (int i = 0; i < 4; ++i) {
        const int c = tid * 4 + i;
        orow[c] = f2b((v[i] - mu) * rstd * g[c] + b[c]);
    }
}

// ---------------- GEMM-256: C[M,N] = A @ Bt^T, 256x128 tile, 512 thr, bf16 out ----
// EPI 0: plain. EPI 2: + fp32 bias + exact GELU.
template <int EPI>
__global__ __launch_bounds__(512) void gemm256(const bf16* __restrict__ A,
                                               const bf16* __restrict__ Bt,
                                               const float* __restrict__ bias,
                                               bf16* __restrict__ C,
                                               int M, int N, int K) {
    constexpr int ASZ = 256 * 32, BSZ = 128 * 32;   // elems per buffer
    constexpr int CST = 128 + 8;                    // epilogue stage stride
    __shared__ __align__(16) bf16 smem[2 * (ASZ + BSZ)];  // 48 KB

    const int Mtiles = M / 256;
    const int p = blockIdx.x;
    const int tm = p % Mtiles;          // tm-fast: few A strips per XCD
    const int tn = p / Mtiles;
    const int tid = threadIdx.x;
    const int wave = tid >> 6, lane = tid & 63;
    const int wm = wave >> 1, wn = wave & 1;
    const int quad = lane >> 4, l16 = lane & 15;

    f32x4 acc[4][4];
#pragma unroll
    for (int i = 0; i < 4; ++i)
#pragma unroll
        for (int j = 0; j < 4; ++j) acc[i][j] = (f32x4){0.f, 0.f, 0.f, 0.f};

    const int s_row = tid >> 2, s_seg = (tid & 3) * 8;
    const bf16* ApLo = A + (size_t)(tm * 256 + s_row) * K + s_seg;
    const size_t K128 = (size_t)128 * K;
    const bf16* Bp = Bt + (size_t)(tn * 128 + s_row) * K + s_seg;

    gld_lds16(ApLo, smem + tid * 8);
    gld_lds16(ApLo + K128, smem + (512 + tid) * 8);
    gld_lds16(Bp, smem + 2 * ASZ + tid * 8);
    ApLo += 32;
    Bp += 32;

    const int nk = K / 32;
    for (int kt = 0; kt < nk; ++kt) {
        const int cur = kt & 1, nxt = cur ^ 1;
        bf16* Acur = smem + cur * ASZ;
        bf16* Bcur = smem + 2 * ASZ + cur * BSZ;
        __syncthreads();
        if (kt + 1 < nk) {
            bf16* Anxt = smem + nxt * ASZ;
            bf16* Bnxt = smem + 2 * ASZ + nxt * BSZ;
            gld_lds16(ApLo, Anxt + tid * 8);
            gld_lds16(ApLo + K128, Anxt + (512 + tid) * 8);
            gld_lds16(Bp, Bnxt + tid * 8);
            ApLo += 32;
            Bp += 32;
        }

        bf16x8 aF[4], bF[4];
#pragma unroll
        for (int mt = 0; mt < 4; ++mt)
            aF[mt] = *(const bf16x8*)(Acur + (wm * 64 + mt * 16 + l16) * 32 + quad * 8);
#pragma unroll
        for (int nt = 0; nt < 4; ++nt)
            bF[nt] = *(const bf16x8*)(Bcur + (wn * 64 + nt * 16 + l16) * 32 + quad * 8);
#pragma unroll
        for (int mt = 0; mt < 4; ++mt)
#pragma unroll
            for (int nt = 0; nt < 4; ++nt)
                acc[mt][nt] = __builtin_amdgcn_mfma_f32_16x16x32_bf16(
                    aF[mt], bF[nt], acc[mt][nt], 0, 0, 0);
    }

#pragma unroll
    for (int hh = 0; hh < 2; ++hh) {
        __syncthreads();
        if ((wm >> 1) == hh) {
#pragma unroll
            for (int nt = 0; nt < 4; ++nt) {
                const int ccol = wn * 64 + nt * 16 + l16;
                float bv = 0.f;
                if (EPI == 2) bv = bias[tn * 128 + ccol];
#pragma unroll
                for (int mt = 0; mt < 4; ++mt) {
                    const int r0 = (wm & 1) * 64 + mt * 16 + quad * 4;
#pragma unroll
                    for (int j = 0; j < 4; ++j) {
                        float v = acc[mt][nt][j];
                        if (EPI == 2) {
                            v += bv;
                            v = 0.5f * v * (1.0f + erff(v * 0.70710678118654752f));
                        }
                        smem[(r0 + j) * CST + ccol] = f2b(v);
                    }
                }
            }
        }
        __syncthreads();
        bf16* crow = C + (size_t)(tm * 256 + hh * 128) * N + tn * 128;
#pragma unroll
        for (int i = 0; i < 4; ++i) {
            const int gid = i * 512 + tid;
            const int row = gid >> 4, c8 = gid & 15;
            const int4 val = *(const int4*)(smem + row * CST + c8 * 8);
            *(int4*)(crow + (size_t)row * N + c8 * 8) = val;
        }
    }
}

// ---------------- GEMM: C[M,N] = A[M,K] @ Bt[N,K]^T  (128x64, 256 thr) ----------
// EPI 1: + fp32 bias + fp32 residual, fp32 out (res==C in-place OK). Wo and W2.
template <int EPI, int BN, int TPB>
__global__ __launch_bounds__(256) void gemm_bt(const bf16* __restrict__ A,
                                               const bf16* __restrict__ Bt,
                                               const float* __restrict__ bias,
                                               const float* __restrict__ res,
                                               void* __restrict__ Cv,
                                               int M, int N, int K) {
    constexpr int NTW = BN / 32;
    constexpr int ASZ = 128 * 32, BSZ = BN * 32;
    __shared__ __align__(16) bf16 smem[2 * (ASZ + BSZ)];

    const int Mtiles = M / 128;
    const int p = blockIdx.x;
    const int tm = p % Mtiles;
    const int tn0 = (p / Mtiles) * TPB;
    const int tid = threadIdx.x;
    const int wave = tid >> 6, lane = tid & 63;
    const int wm = wave >> 1, wn = wave & 1;
    const int quad = lane >> 4, l16 = lane & 15;

    const int s_row = tid >> 2, s_seg = (tid & 3) * 8;
    const size_t K64 = (size_t)64 * K;
    const int nk = K / 32;

    for (int tp = 0; tp < TPB; ++tp) {
        const int tn = tn0 + tp;
        if (tp) __syncthreads();

        f32x4 acc[4][NTW];
#pragma unroll
        for (int i = 0; i < 4; ++i)
#pragma unroll
            for (int j = 0; j < NTW; ++j) acc[i][j] = (f32x4){0.f, 0.f, 0.f, 0.f};

        const bf16* Ap = A + (size_t)(tm * 128 + s_row) * K + s_seg;
        const bf16* Bp = Bt + (size_t)(tn * BN + s_row) * K + s_seg;

        gld_lds16(Ap, smem + tid * 8);
        gld_lds16(Ap + K64, smem + (256 + tid) * 8);
        gld_lds16(Bp, smem + 2 * ASZ + tid * 8);
        if constexpr (BN == 128) gld_lds16(Bp + K64, smem + 2 * ASZ + (256 + tid) * 8);
        Ap += 32;
        Bp += 32;

        for (int kt = 0; kt < nk; ++kt) {
            const int cur = kt & 1, nxt = cur ^ 1;
            bf16* Acur = smem + cur * ASZ;
            bf16* Bcur = smem + 2 * ASZ + cur * BSZ;
            __syncthreads();
            if (kt + 1 < nk) {
                bf16* Anxt = smem + nxt * ASZ;
                bf16* Bnxt = smem + 2 * ASZ + nxt * BSZ;
                gld_lds16(Ap, Anxt + tid * 8);
                gld_lds16(Ap + K64, Anxt + (256 + tid) * 8);
                gld_lds16(Bp, Bnxt + tid * 8);
                if constexpr (BN == 128) gld_lds16(Bp + K64, Bnxt + (256 + tid) * 8);
                Ap += 32;
                Bp += 32;
            }

            bf16x8 aF[4], bF[NTW];
#pragma unroll
            for (int mt = 0; mt < 4; ++mt)
                aF[mt] = *(const bf16x8*)(Acur + (wm * 64 + mt * 16 + l16) * 32 + quad * 8);
#pragma unroll
            for (int nt = 0; nt < NTW; ++nt)
                bF[nt] = *(const bf16x8*)(Bcur + (wn * (BN / 2) + nt * 16 + l16) * 32 + quad * 8);
#pragma unroll
            for (int mt = 0; mt < 4; ++mt)
#pragma unroll
                for (int nt = 0; nt < NTW; ++nt)
                    acc[mt][nt] = __builtin_amdgcn_mfma_f32_16x16x32_bf16(
                        aF[mt], bF[nt], acc[mt][nt], 0, 0, 0);
        }

#pragma unroll
        for (int nt = 0; nt < NTW; ++nt) {
            const int col = tn * BN + wn * (BN / 2) + nt * 16 + l16;
            const float bv = bias[col];
#pragma unroll
            for (int mt = 0; mt < 4; ++mt) {
                const int row0 = tm * 128 + wm * 64 + mt * 16 + quad * 4;
#pragma unroll
                for (int j = 0; j < 4; ++j) {
                    const size_t idx = (size_t)(row0 + j) * N + col;
                    ((float*)Cv)[idx] = acc[mt][nt][j] + bv + res[idx];
                }
            }
        }
    }
}

// ---------------- MFMA flash attention (causal), 4 blocks/CU, all co-resident ----
// Grid 1024 (1-D): bh = id&31 (id%8 = bh%8 -> per-head XCD locality), k = id>>5,
// t = k<16 ? 31-k : k-16 (CU gets blocks {k,k+8,k+16,k+24} -> nch sums to 66:
// perfectly static balance, zero tail). 256 threads = 4 waves x 16 q-rows = one
// 64-query tile; nch = t+1 chunks of 64 keys; K/V dbuf, distance-1 prefetch.
//
// SWAPPED-OPERAND + PERMUTED-KEY layout: QK^T mfma m loads K-rows in permuted
// order key = (l16>>2)*8 + (m&1)*4 + (l16&3) (+ (m>>1)*32), so the score output
// lands with lane (quad,l16) holding keys quad*8+0..7 (+32) for q=l16 — exactly
// the PV B-fragment layout. P packs into aP0/aP1 IN REGISTERS: no P-LDS, no
// shuffles, no lgkmcnt. LDS = Ks(16K)+Vt(18K) = 34.8 KB -> 4 blocks/CU.
// K-LDS swizzle s(k)=(k&3)|((k>>1)&4) keeps permuted reads 2-way-conflict-free.
__global__ __launch_bounds__(256) void fattn_kernel(const bf16* __restrict__ QKV,
                                                    bf16* __restrict__ ctx) {
    const int id = blockIdx.x;
    const int bh = id & 31;
    const int k = id >> 5;          // 0..31
    const int t = (k < 16) ? 31 - k : k - 16;
    const int b = bh >> 4, h = bh & (H - 1);
    const int tid = threadIdx.x;
    const int wave = tid >> 6, lane = tid & 63;
    const int quad = lane >> 4, l16 = lane & 15;
    const bf16* Qp = QKV + (size_t)b * S * DQ + h * HD;
    const bf16* Kp = Qp + D;
    const bf16* Vp = Qp + 2 * D;

    __shared__ __align__(16) bf16 Ks[2][64 * 64];  // [key][seg], seg-swizzled
    __shared__ __align__(16) bf16 Vt[2][64][72];   // [d][key]

    // K staging: 2 slots (16B)/thread: slots tid and tid+256 (key+32, same seg).
    // LDS seg g of key holds global dseg g ^ s(key), s(k) = (k&3)|((k>>1)&4).
    const int keyA = tid >> 3;
    const int sA = (keyA & 3) | ((keyA >> 1) & 4);
    const int dsA = ((tid & 7) ^ sA) * 8;
    const size_t K32 = (size_t)32 * DQ;

    const int q0 = t * 64;
    // Q fragments, pre-scaled by 1/sqrt(64); wave w owns q-rows [w*16, w*16+16)
    const bf16* qg = Qp + (size_t)(q0 + wave * 16 + l16) * DQ + quad * 8;
    union U8 { bf16 h[8]; bf16x8 v; };
    U8 uq0, uq1;
    uq0.v = *(const bf16x8*)(qg);
    uq1.v = *(const bf16x8*)(qg + 32);
#pragma unroll
    for (int i = 0; i < 8; ++i) {
        uq0.h[i] = f2b(__bfloat162float(uq0.h[i]) * 0.125f);
        uq1.h[i] = f2b(__bfloat162float(uq1.h[i]) * 0.125f);
    }
    const bf16x8 aQ0 = uq0.v;
    const bf16x8 aQ1 = uq1.v;

    // QK^T read offsets: mfma m reads K-rows k_m = kb + (m&1)*4 + (m>>1)*32;
    // s(k_m) = sQ for all m. Elem offset = k_m*64 + ((g ^ sQ)*8), g = quad / 4+quad.
    const int kb = (l16 >> 2) * 8 + (l16 & 3);
    const int sQ = (l16 & 3) | (((l16 >> 2) & 1) << 2);
    const int ofs0 = kb * 64 + ((quad ^ sQ) * 8);
    const int ofs1 = kb * 64 + (((4 + quad) ^ sQ) * 8);

    f32x4 O[4];   // O[nt][j] = O[d = nt*16+quad*4+j][q = l16]
#pragma unroll
    for (int nt = 0; nt < 4; ++nt) O[nt] = (f32x4){0.f, 0.f, 0.f, 0.f};
    float rowm = -3.0e38f, rowl = 0.f;

    // pre-stage chunk 0 into buffer 0
    gld_lds16(Kp + (size_t)keyA * DQ + dsA, Ks[0] + tid * 8);
    gld_lds16(Kp + K32 + (size_t)keyA * DQ + dsA, Ks[0] + (256 + tid) * 8);
    {
        // V: wave w stages d in [w*16, w*16+16), key = lane
        const bf16* vg = Vp + (size_t)lane * DQ + wave * 16;
        U8 u0, u1;
        u0.v = *(const bf16x8*)vg;
        u1.v = *(const bf16x8*)(vg + 8);
#pragma unroll
        for (int i = 0; i < 8; ++i) {
            Vt[0][wave * 16 + i][lane] = u0.h[i];
            Vt[0][wave * 16 + 8 + i][lane] = u1.h[i];
        }
    }

    const int nch = t + 1;
    for (int c = 0; c < nch; ++c) {
        const int cur = c & 1, nxt = cur ^ 1;
        __syncthreads();  // buf[cur] ready (drains prefetch vmcnt + V lgkm)
        U8 u0, u1;
        if (c + 1 < nch) {
            const bf16* kg = Kp + (size_t)((c + 1) * 64 + keyA) * DQ + dsA;
            gld_lds16(kg, Ks[nxt] + tid * 8);
            gld_lds16(kg + K32, Ks[nxt] + (256 + tid) * 8);
            const bf16* vg = Vp + (size_t)((c + 1) * 64 + lane) * DQ + wave * 16;
            u0.v = *(const bf16x8*)vg;
            u1.v = *(const bf16x8*)(vg + 8);
        }

        // scores: sc[m][j] = S[key = quad*8 + (m&1)*4 + (m>>1)*32 + j][q = l16]
        f32x4 sc[4];
        __builtin_amdgcn_s_setprio(1);
#pragma unroll
        for (int m = 0; m < 4; ++m) {
            const bf16* kr = Ks[cur] + (m & 1) * 256 + (m >> 1) * 2048;
            const bf16x8 bK0 = *(const bf16x8*)(kr + ofs0);
            const bf16x8 bK1 = *(const bf16x8*)(kr + ofs1);
            f32x4 z = (f32x4){0.f, 0.f, 0.f, 0.f};
            z = __builtin_amdgcn_mfma_f32_16x16x32_bf16(bK0, aQ0, z, 0, 0, 0);
            z = __builtin_amdgcn_mfma_f32_16x16x32_bf16(bK1, aQ1, z, 0, 0, 0);
            sc[m] = z;
        }
        __builtin_amdgcn_s_setprio(0);
        // causal mask — only the last chunk intersects the diagonal band
        if (c == nch - 1) {
            const int qloc = wave * 16 + l16;
#pragma unroll
            for (int m = 0; m < 4; ++m) {
                const int kk = quad * 8 + (m & 1) * 4 + (m >> 1) * 32;
#pragma unroll
                for (int j = 0; j < 4; ++j)
                    if (kk + j > qloc) sc[m][j] = -3.0e38f;
            }
        }
        // online softmax, lane-local row (q = l16); reduce across quads only
        f32x4 mv;
#pragma unroll
        for (int j = 0; j < 4; ++j)
            mv[j] = fmaxf(fmaxf(sc[0][j], sc[1][j]), fmaxf(sc[2][j], sc[3][j]));
        float mx = fmaxf(fmaxf(mv[0], mv[1]), fmaxf(mv[2], mv[3]));
        mx = fmaxf(mx, __shfl_xor(mx, 16));
        mx = fmaxf(mx, __shfl_xor(mx, 32));
        const float mn = fmaxf(rowm, mx);
        const float alq = __expf(rowm - mn);
        rowm = mn;
        float rs = 0.f;
#pragma unroll
        for (int m = 0; m < 4; ++m)
#pragma unroll
            for (int j = 0; j < 4; ++j) {
                sc[m][j] = __expf(sc[m][j] - mn);
                rs += sc[m][j];
            }
        rs += __shfl_xor(rs, 16);
        rs += __shfl_xor(rs, 32);
        rowl = rowl * alq + rs;

        // P packs DIRECTLY into PV B-fragments (keys quad*8+e / 32+quad*8+e)
        U8 p0, p1;
#pragma unroll
        for (int j = 0; j < 4; ++j) {
            p0.h[j]     = f2b(sc[0][j]);
            p0.h[4 + j] = f2b(sc[1][j]);
            p1.h[j]     = f2b(sc[2][j]);
            p1.h[4 + j] = f2b(sc[3][j]);
        }
        // O = O*alpha + V^T P
#pragma unroll
        for (int nt = 0; nt < 4; ++nt)
#pragma unroll
            for (int j = 0; j < 4; ++j) O[nt][j] *= alq;
        __builtin_amdgcn_s_setprio(1);
#pragma unroll
        for (int nt = 0; nt < 4; ++nt) {
            const bf16x8 bV0 = *(const bf16x8*)&Vt[cur][nt * 16 + l16][quad * 8];
            const bf16x8 bV1 = *(const bf16x8*)&Vt[cur][nt * 16 + l16][32 + quad * 8];
            O[nt] = __builtin_amdgcn_mfma_f32_16x16x32_bf16(bV0, p0.v, O[nt], 0, 0, 0);
            O[nt] = __builtin_amdgcn_mfma_f32_16x16x32_bf16(bV1, p1.v, O[nt], 0, 0, 0);
        }
        __builtin_amdgcn_s_setprio(0);
        // commit prefetched V into buf[nxt]
        if (c + 1 < nch) {
#pragma unroll
            for (int i = 0; i < 8; ++i) {
                Vt[nxt][wave * 16 + i][lane] = u0.h[i];
                Vt[nxt][wave * 16 + 8 + i][lane] = u1.h[i];
            }
        }
    }

    // finalize: lane holds q = l16, d = nt*16+quad*4+j; 8B stores per nt
    const float rlq = 1.0f / rowl;
    bf16* crow = ctx + (size_t)b * S * D + h * HD + (size_t)(q0 + wave * 16 + l16) * D;
#pragma unroll
    for (int nt = 0; nt < 4; ++nt) {
        union { bf16 h[4]; int2 v; } o;
#pragma unroll
        for (int j = 0; j < 4; ++j) o.h[j] = f2b(O[nt][j] * rlq);
        *(int2*)(crow + nt * 16 + quad * 4) = o.v;
    }
}

// ---------------- launcher ----------------
extern "C" void kernel_launch(void* const* d_in, const int* in_sizes, int n_in,
                              void* d_out, int out_size, void* d_ws, size_t ws_size,
                              hipStream_t stream) {
    const float* x     = (const float*)d_in[0];
    const float* ln1_g = (const float*)d_in[1];
    const float* ln1_b = (const float*)d_in[2];
    const float* Wq    = (const float*)d_in[3];
    const float* Wk    = (const float*)d_in[4];
    const float* Wv    = (const float*)d_in[5];
    const float* Wo    = (const float*)d_in[6];
    const float* bo    = (const float*)d_in[7];
    const float* ln2_g = (const float*)d_in[8];
    const float* ln2_b = (const float*)d_in[9];
    const float* W1    = (const float*)d_in[10];
    const float* b1    = (const float*)d_in[11];
    const float* W2    = (const float*)d_in[12];
    const float* b2    = (const float*)d_in[13];
    float* out = (float*)d_out;

    // workspace (MB), lifetime-overlapped; peak 64 MB:
    //   [ 0, 8): h (LN1 out)            -> W1T (conv after QKV gemm)
    //   [ 8,32): QKVb (packed, 24 MB)   \
    //   [32,40): ctx (attn out)          } -> hff [8,40) (32 MB)
    //   [40,48): h2 (LN2 out)
    //   [48,54): WqkvT   [54,56): WoT   [56,64): W2T
    //   x2 (fp32 residual) lives in d_out; final GEMM reads it in-place.
    char* ws = (char*)d_ws;
    const size_t MB = (size_t)1 << 20;
    bf16* h     = (bf16*)(ws + 0 * MB);
    bf16* W1T   = (bf16*)(ws + 0 * MB);
    bf16* QKVb  = (bf16*)(ws + 8 * MB);
    bf16* hff   = (bf16*)(ws + 8 * MB);
    bf16* ctx   = (bf16*)(ws + 32 * MB);
    bf16* h2    = (bf16*)(ws + 40 * MB);
    bf16* WqkvT = (bf16*)(ws + 48 * MB);
    bf16* WoT   = (bf16*)(ws + 54 * MB);
    bf16* W2T   = (bf16*)(ws + 56 * MB);

    // --- 0) transpose-convert the 5 x-independent weights in ONE dispatch ---
    convT5_kernel<<<2048, 256, 0, stream>>>(Wq, Wk, Wv, Wo, W2, WqkvT, WoT, W2T);
    // --- 1) LN1 ---
    ln_kernel<<<NR, 256, 0, stream>>>(x, ln1_g, ln1_b, h);
    // --- 2) QKV = h @ [Wq|Wk|Wv]   [4096,1024]x[1024,3072], 384 big blocks ---
    gemm256<0><<<(NR / 256) * (DQ / 128), 512, 0, stream>>>(
        h, WqkvT, nullptr, QKVb, NR, DQ, D);
    // h dead now -> W1T into [0,8)
    convT_kernel<<<dim3(16, 64), 256, 0, stream>>>(W1, W1T, D, DFF);
    // --- 3) flash attention -> ctx (1024 blocks, 4/CU, all co-resident) ---
    fattn_kernel<<<dim3((S / 64) * B * H), 256, 0, stream>>>(QKVb, ctx);
    // --- 4) x2 = x + ctx @ Wo + bo   (fp32 into d_out), 512 blocks ---
    gemm_bt<1, 64, 1><<<(NR / 128) * (D / 64), 256, 0, stream>>>(
        ctx, WoT, bo, x, out, NR, D, D);
    // --- 5) LN2 ---
    ln_kernel<<<NR, 256, 0, stream>>>(out, ln2_g, ln2_b, h2);
    // --- 6) hff = gelu(h2 @ W1 + b1), 512 big blocks (2/CU, one generation) ---
    gemm256<2><<<(NR / 256) * (DFF / 128), 512, 0, stream>>>(
        h2, W1T, b1, hff, NR, DFF, D);
    // --- 7) out = x2 + hff @ W2 + b2   [4096,4096]x[4096,1024], in-place ---
    gemm_bt<1, 64, 1><<<(NR / 128) * (D / 64), 256, 0, stream>>>(
        hff, W2T, b2, out, out, NR, D, DFF);
}